// Round 5
// baseline (421.646 us; speedup 1.0000x reference)
//
#include <hip/hip_runtime.h>
#include <hip/hip_bf16.h>
#include <math.h>
#include <stdint.h>

#define NEG_SLOPE 0.2f
#define BN_EPS 1e-5f

typedef __attribute__((ext_vector_type(8))) short short8;
typedef __attribute__((ext_vector_type(4))) float float4v;

static __device__ __forceinline__ unsigned short f2bf(float f) {
    union { float f; unsigned u; } v; v.f = f;
    unsigned r = (v.u + 0x7fffu + ((v.u >> 16) & 1u)) >> 16;  // RNE
    return (unsigned short)r;
}
static __device__ __forceinline__ float bf2f(unsigned short u) {
    union { unsigned u; float f; } v; v.u = ((unsigned)u) << 16;
    return v.f;
}

// ---------------------------------------------------------------------------
// BN constant prep
// ---------------------------------------------------------------------------
__global__ __launch_bounds__(128) void bn_prep(const float* __restrict__ gamma,
                                               const float* __restrict__ beta,
                                               const float* __restrict__ rmean,
                                               const float* __restrict__ rvar,
                                               float* __restrict__ scale,
                                               float* __restrict__ shift) {
    int c = threadIdx.x;
    float s = gamma[c] * rsqrtf(rvar[c] + BN_EPS);
    scale[c] = s;
    shift[c] = beta[c] - rmean[c] * s;
}

// ---------------------------------------------------------------------------
// one-time: WT[n*128+k] = bf16(W[k*128+n])   (pre-transposed B for MFMA)
// ---------------------------------------------------------------------------
__global__ __launch_bounds__(256) void w_to_bf16T(const float* __restrict__ W,
                                                  unsigned short* __restrict__ WT) {
    int idx = blockIdx.x * 256 + threadIdx.x;  // 16384 total
    int k = idx >> 7, n = idx & 127;
    WT[n * 128 + k] = f2bf(W[idx]);
}

// ---------------------------------------------------------------------------
// CSR build
// ---------------------------------------------------------------------------
__global__ __launch_bounds__(256) void count_deg(const int* __restrict__ dst,
                                                 int* __restrict__ deg, int E) {
    int i = blockIdx.x * 256 + threadIdx.x;
    if (i < E) atomicAdd(&deg[dst[i]], 1);
}

__global__ __launch_bounds__(256) void scan_block_reduce(const int* __restrict__ deg,
                                                         int* __restrict__ bsum, int N) {
    __shared__ int s[256];
    int t = threadIdx.x;
    int i = blockIdx.x * 256 + t;
    s[t] = (i < N) ? deg[i] : 0;
    __syncthreads();
#pragma unroll
    for (int d = 128; d; d >>= 1) {
        if (t < d) s[t] += s[t + d];
        __syncthreads();
    }
    if (t == 0) bsum[blockIdx.x] = s[0];
}

__global__ __launch_bounds__(1024) void scan_block_sums(int* __restrict__ bsum,
                                                        int* __restrict__ offs,
                                                        int nb, int N) {
    __shared__ int s[1024];
    int t = threadIdx.x;
    int v = (t < nb) ? bsum[t] : 0;
    s[t] = v;
    __syncthreads();
    for (int d = 1; d < 1024; d <<= 1) {
        int u = (t >= d) ? s[t - d] : 0;
        __syncthreads();
        s[t] += u;
        __syncthreads();
    }
    if (t < nb) bsum[t] = s[t] - v;       // exclusive block base
    if (t == 1023) offs[N] = s[1023];     // total == E
}

__global__ __launch_bounds__(256) void scan_write_offsets(const int* __restrict__ deg,
                                                          const int* __restrict__ bsum,
                                                          int* __restrict__ offs, int N) {
    __shared__ int s[256];
    int t = threadIdx.x;
    int i = blockIdx.x * 256 + t;
    int v = (i < N) ? deg[i] : 0;
    s[t] = v;
    __syncthreads();
    for (int d = 1; d < 256; d <<= 1) {
        int u = (t >= d) ? s[t - d] : 0;
        __syncthreads();
        s[t] += u;
        __syncthreads();
    }
    if (i < N) offs[i] = bsum[blockIdx.x] + s[t] - v;
}

__global__ __launch_bounds__(256) void fill_csr(const int* __restrict__ src,
                                                const int* __restrict__ dst,
                                                const int* __restrict__ off,
                                                int* __restrict__ cursor,
                                                int* __restrict__ csr_src, int E) {
    int i = blockIdx.x * 256 + threadIdx.x;
    if (i < E) {
        int d = dst[i];
        int p = atomicAdd(&cursor[d], 1);
        csr_src[off[d] + p] = src[i];
    }
}

// ---------------------------------------------------------------------------
// H(bf16) = X @ W via MFMA bf16 (fp32 accum), node_scores fused in epilogue.
// Templated input: fp32 (layer 1: embedding) or bf16 (layer 2: x1).
// ---------------------------------------------------------------------------
#define LP_RS 136  // LDS row stride in bf16 elements (272 bytes)

template <bool BF16_IN>
__global__ __launch_bounds__(256) void gemm_mfma(
    const void* __restrict__ Xv,
    const unsigned short* __restrict__ WT,  // [n][k] bf16 (pre-transposed)
    const float* __restrict__ a_src, const float* __restrict__ a_dst,
    unsigned short* __restrict__ H,         // bf16 out
    float* __restrict__ s_src, float* __restrict__ s_dst, int N)
{
    __shared__ unsigned short sA[128 * LP_RS];
    __shared__ unsigned short sW[128 * LP_RS];
    const float* Xf = (const float*)Xv;
    const unsigned short* Xh = (const unsigned short*)Xv;
    int tid = threadIdx.x;
    int r0 = blockIdx.x * 128;

#pragma unroll
    for (int it = 0; it < 8; ++it) {
        int idx = it * 2048 + tid * 8;
        int n = idx >> 7, k = idx & 127;
        *(short8*)&sW[n * LP_RS + k] = *(const short8*)&WT[idx];
    }
#pragma unroll
    for (int it = 0; it < 16; ++it) {
        int r = it * 8 + (tid >> 5);
        int c = (tid & 31) * 4;
        int row = r0 + r;
        ushort4 u = make_ushort4(0, 0, 0, 0);
        if (row < N) {
            if (BF16_IN) {
                u = *(const ushort4*)&Xh[(size_t)row * 128 + c];
            } else {
                float4 x = *(const float4*)&Xf[(size_t)row * 128 + c];
                u.x = f2bf(x.x); u.y = f2bf(x.y); u.z = f2bf(x.z); u.w = f2bf(x.w);
            }
        }
        *(ushort4*)&sA[r * LP_RS + c] = u;
    }
    __syncthreads();

    int wave = tid >> 6, lane = tid & 63;
    int ln = lane & 15, quad = lane >> 4;
    int rowbase = wave * 32;

    short8 af[2][4];
#pragma unroll
    for (int m = 0; m < 2; ++m)
#pragma unroll
        for (int kt = 0; kt < 4; ++kt)
            af[m][kt] = *(const short8*)&sA[(rowbase + m * 16 + ln) * LP_RS + kt * 32 + quad * 8];

    float4v acc[2][8];
#pragma unroll
    for (int m = 0; m < 2; ++m)
#pragma unroll
        for (int n = 0; n < 8; ++n)
            acc[m][n] = float4v{0.f, 0.f, 0.f, 0.f};

#pragma unroll
    for (int n = 0; n < 8; ++n) {
#pragma unroll
        for (int kt = 0; kt < 4; ++kt) {
            short8 bf = *(const short8*)&sW[(n * 16 + ln) * LP_RS + kt * 32 + quad * 8];
            acc[0][n] = __builtin_amdgcn_mfma_f32_16x16x32_bf16(af[0][kt], bf, acc[0][n], 0, 0, 0);
            acc[1][n] = __builtin_amdgcn_mfma_f32_16x16x32_bf16(af[1][kt], bf, acc[1][n], 0, 0, 0);
        }
    }

    // epilogue: store H bf16 (C/D layout: col=ln, row=quad*4+reg) + fused scores
    float asr[8], adr[8];
#pragma unroll
    for (int n = 0; n < 8; ++n) {
        asr[n] = a_src[n * 16 + ln];
        adr[n] = a_dst[n * 16 + ln];
    }
#pragma unroll
    for (int m = 0; m < 2; ++m) {
        int rb = r0 + rowbase + m * 16 + quad * 4;
#pragma unroll
        for (int n = 0; n < 8; ++n) {
            int col = n * 16 + ln;
            float4v a = acc[m][n];
            if (rb + 0 < N) H[(size_t)(rb + 0) * 128 + col] = f2bf(a[0]);
            if (rb + 1 < N) H[(size_t)(rb + 1) * 128 + col] = f2bf(a[1]);
            if (rb + 2 < N) H[(size_t)(rb + 2) * 128 + col] = f2bf(a[2]);
            if (rb + 3 < N) H[(size_t)(rb + 3) * 128 + col] = f2bf(a[3]);
        }
#pragma unroll
        for (int r = 0; r < 4; ++r) {
            float ps = 0.f, pd = 0.f;
#pragma unroll
            for (int n = 0; n < 8; ++n) {
                float v = acc[m][n][r];
                ps = fmaf(v, asr[n], ps);
                pd = fmaf(v, adr[n], pd);
            }
#pragma unroll
            for (int o = 1; o < 16; o <<= 1) {
                ps += __shfl_xor(ps, o);
                pd += __shfl_xor(pd, o);
            }
            int row = rb + r;
            if (ln == 0 && row < N) { s_src[row] = ps; s_dst[row] = pd; }
        }
    }
}

// ---------------------------------------------------------------------------
// Per-edge softmax weights, quad (16 lanes) per node
// ---------------------------------------------------------------------------
__global__ __launch_bounds__(256) void edge_softmax(const int* __restrict__ off,
                                                    const int* __restrict__ csr,
                                                    const float* __restrict__ s_src,
                                                    const float* __restrict__ s_dst,
                                                    float* __restrict__ we,
                                                    float* __restrict__ invd, int N) {
    int tid = threadIdx.x;
    int node = blockIdx.x * 16 + (tid >> 4);
    if (node >= N) return;
    int ln = tid & 15;
    int beg = off[node], end = off[node + 1];
    float sd = s_dst[node];

    float m = -INFINITY;
    for (int i = beg + ln; i < end; i += 16) {
        float e = s_src[csr[i]] + sd;
        e = (e >= 0.f) ? e : NEG_SLOPE * e;
        we[i] = e;
        m = fmaxf(m, e);
    }
#pragma unroll
    for (int o = 8; o; o >>= 1) m = fmaxf(m, __shfl_xor(m, o));

    float sw = 0.f;
    for (int i = beg + ln; i < end; i += 16) {
        float w = expf(we[i] - m);
        we[i] = w;
        sw += w;
    }
#pragma unroll
    for (int o = 8; o; o >>= 1) sw += __shfl_xor(sw, o);
    if (ln == 0) invd[node] = 1.f / (sw + 1e-16f);
}

// ---------------------------------------------------------------------------
// Weighted gather over bf16 H: out_bf16[n,:] = (sum we*h)*invd + bias (+BN/ReLU)
// One wave per node, lanes = 2 channels (ushort2 = 4 B); 8-edge unroll.
// ---------------------------------------------------------------------------
__global__ __launch_bounds__(256) void gat_gather(const unsigned short* __restrict__ H,
                                                  const int* __restrict__ off,
                                                  const int* __restrict__ csr,
                                                  const float* __restrict__ we,
                                                  const float* __restrict__ invd,
                                                  const float* __restrict__ bias,
                                                  const float* __restrict__ bn_scale,
                                                  const float* __restrict__ bn_shift,
                                                  int do_bn_relu,
                                                  unsigned short* __restrict__ out, int N) {
    int node = blockIdx.x * 4 + (threadIdx.x >> 6);
    if (node >= N) return;
    int lane = threadIdx.x & 63;
    int c0 = lane * 2;
    int beg = off[node], end = off[node + 1];
    float inv = invd[node];

    float accx = 0.f, accy = 0.f;
    int i = beg;
    for (; i + 8 <= end; i += 8) {
#pragma unroll
        for (int u = 0; u < 8; ++u) {
            int s = csr[i + u];
            float w = we[i + u];
            ushort2 hv = *(const ushort2*)&H[(size_t)s * 128 + c0];
            accx = fmaf(w, bf2f(hv.x), accx);
            accy = fmaf(w, bf2f(hv.y), accy);
        }
    }
    for (; i < end; ++i) {
        int s = csr[i];
        float w = we[i];
        ushort2 hv = *(const ushort2*)&H[(size_t)s * 128 + c0];
        accx = fmaf(w, bf2f(hv.x), accx);
        accy = fmaf(w, bf2f(hv.y), accy);
    }
    float o0 = accx * inv + bias[c0];
    float o1 = accy * inv + bias[c0 + 1];
    if (do_bn_relu) {
        o0 = fmaxf(o0 * bn_scale[c0] + bn_shift[c0], 0.f);
        o1 = fmaxf(o1 * bn_scale[c0 + 1] + bn_shift[c0 + 1], 0.f);
    }
    ushort2 ov; ov.x = f2bf(o0); ov.y = f2bf(o1);
    *(ushort2*)&out[(size_t)node * 128 + c0] = ov;
}

// ---------------------------------------------------------------------------
// Link predictor v2: persistent waves, sW staged once/block, A-fragments
// gathered direct-to-register from bf16 X in MFMA layout, per-n acc consume.
// Each wave handles 32 queries per tile; grid-stride over tiles; no barriers
// in the tile loop.
// ---------------------------------------------------------------------------
__global__ __launch_bounds__(256, 4) void link_pred_mfma(
    const unsigned short* __restrict__ X,   // bf16 x2 [N][128]
    const int* __restrict__ E0, const int* __restrict__ E1,
    const unsigned short* __restrict__ WTg, // [n][k] bf16
    const float* __restrict__ bp1,
    const float* __restrict__ Wp2,
    const float* __restrict__ bp2_p,
    float* __restrict__ out, int Q)
{
    __shared__ unsigned short sW[128 * LP_RS];
    int tid = threadIdx.x;
#pragma unroll
    for (int it = 0; it < 8; ++it) {
        int idx = it * 2048 + tid * 8;
        int n = idx >> 7, k = idx & 127;
        *(short8*)&sW[n * LP_RS + k] = *(const short8*)&WTg[idx];
    }
    __syncthreads();

    int wave = tid >> 6, lane = tid & 63;
    int ln = lane & 15, quad = lane >> 4;

    float bias[8], w2c[8];
#pragma unroll
    for (int n = 0; n < 8; ++n) {
        bias[n] = bp1[n * 16 + ln];
        w2c[n] = Wp2[n * 16 + ln];
    }
    float b2 = bp2_p[0];

    int ntiles = (Q + 31) >> 5;
    int tile0 = blockIdx.x * 4 + wave;
    int tstride = gridDim.x * 4;

    for (int t = tile0; t < ntiles; t += tstride) {
        int qbase = t * 32;
        // A fragments direct from global (layout: A[m=ln][k=quad*8+j], k-tile kt)
        short8 af[2][4];
#pragma unroll
        for (int m = 0; m < 2; ++m) {
            int q = qbase + m * 16 + ln;
            if (q >= Q) q = Q - 1;  // clamp; store is guarded
            int a = E0[q], b = E1[q];
            const unsigned short* pa = &X[(size_t)a * 128 + quad * 8];
            const unsigned short* pb = &X[(size_t)b * 128 + quad * 8];
#pragma unroll
            for (int kt = 0; kt < 4; ++kt) {
                short8 xa = *(const short8*)(pa + kt * 32);
                short8 xb = *(const short8*)(pb + kt * 32);
                short8 p;
#pragma unroll
                for (int j = 0; j < 8; ++j)
                    p[j] = (short)f2bf(bf2f((unsigned short)xa[j]) * bf2f((unsigned short)xb[j]));
                af[m][kt] = p;
            }
        }

        float r0[2] = {0.f, 0.f}, r1[2] = {0.f, 0.f}, r2[2] = {0.f, 0.f}, r3[2] = {0.f, 0.f};
#pragma unroll
        for (int n = 0; n < 8; ++n) {
            float4v a0 = float4v{bias[n], bias[n], bias[n], bias[n]};
            float4v a1 = a0;
#pragma unroll
            for (int kt = 0; kt < 4; ++kt) {
                short8 bf = *(const short8*)&sW[(n * 16 + ln) * LP_RS + kt * 32 + quad * 8];
                a0 = __builtin_amdgcn_mfma_f32_16x16x32_bf16(af[0][kt], bf, a0, 0, 0, 0);
                a1 = __builtin_amdgcn_mfma_f32_16x16x32_bf16(af[1][kt], bf, a1, 0, 0, 0);
            }
            float w = w2c[n];
            r0[0] += fmaxf(a0[0], 0.f) * w;  r0[1] += fmaxf(a1[0], 0.f) * w;
            r1[0] += fmaxf(a0[1], 0.f) * w;  r1[1] += fmaxf(a1[1], 0.f) * w;
            r2[0] += fmaxf(a0[2], 0.f) * w;  r2[1] += fmaxf(a1[2], 0.f) * w;
            r3[0] += fmaxf(a0[3], 0.f) * w;  r3[1] += fmaxf(a1[3], 0.f) * w;
        }
#pragma unroll
        for (int m = 0; m < 2; ++m) {
#pragma unroll
            for (int o = 1; o < 16; o <<= 1) {
                r0[m] += __shfl_xor(r0[m], o);
                r1[m] += __shfl_xor(r1[m], o);
                r2[m] += __shfl_xor(r2[m], o);
                r3[m] += __shfl_xor(r3[m], o);
            }
            if (ln == 0) {
                int rbase = qbase + m * 16 + quad * 4;
                float rv[4] = {r0[m], r1[m], r2[m], r3[m]};
#pragma unroll
                for (int r = 0; r < 4; ++r) {
                    int q = rbase + r;
                    if (q < Q) out[q] = 1.f / (1.f + expf(-(rv[r] + b2)));
                }
            }
        }
    }
}

// ---------------------------------------------------------------------------
extern "C" void kernel_launch(void* const* d_in, const int* in_sizes, int n_in,
                              void* d_out, int out_size, void* d_ws, size_t ws_size,
                              hipStream_t stream) {
    const float* emb    = (const float*)d_in[0];
    const float* W1     = (const float*)d_in[1];
    const float* a_src1 = (const float*)d_in[2];
    const float* a_dst1 = (const float*)d_in[3];
    const float* b1     = (const float*)d_in[4];
    const float* gamma  = (const float*)d_in[5];
    const float* beta   = (const float*)d_in[6];
    const float* rmean  = (const float*)d_in[7];
    const float* rvar   = (const float*)d_in[8];
    const float* W2     = (const float*)d_in[9];
    const float* a_src2 = (const float*)d_in[10];
    const float* a_dst2 = (const float*)d_in[11];
    const float* b2     = (const float*)d_in[12];
    const float* Wp1    = (const float*)d_in[13];
    const float* bp1    = (const float*)d_in[14];
    const float* Wp2    = (const float*)d_in[15];
    const float* bp2    = (const float*)d_in[16];
    const int* edge_index = (const int*)d_in[17];
    const int* edges      = (const int*)d_in[18];

    const int N = in_sizes[0] / 128;
    const int E = in_sizes[17] / 2;
    const int Q = in_sizes[18] / 2;
    const int* src = edge_index;
    const int* dst = edge_index + E;
    const int* e0 = edges;
    const int* e1 = edges + Q;
    float* out = (float*)d_out;

    uintptr_t base = (uintptr_t)d_ws;
    size_t cur = 0;
    auto take = [&](size_t bytes) -> void* {
        void* p = (void*)(base + cur);
        cur += (bytes + 255) & ~(size_t)255;
        return p;
    };
    unsigned short* bufA = (unsigned short*)take((size_t)N * 128 * 2);  // H (bf16)
    unsigned short* bufB = (unsigned short*)take((size_t)N * 128 * 2);  // x (bf16)
    float* s_src  = (float*)take((size_t)N * 4);
    float* s_dst  = (float*)take((size_t)N * 4);
    float* bnsc   = (float*)take(128 * 4);
    float* bnsh   = (float*)take(128 * 4);
    int*   deg    = (int*)take((size_t)N * 4);
    int*   cursor = (int*)take((size_t)N * 4);
    int*   offs   = (int*)take((size_t)(N + 1) * 4);
    int*   csr    = (int*)take((size_t)E * 4);
    float* we     = (float*)take((size_t)E * 4);
    float* invd   = (float*)take((size_t)N * 4);
    unsigned short* wt1 = (unsigned short*)take(128 * 128 * 2);
    unsigned short* wt2 = (unsigned short*)take(128 * 128 * 2);
    unsigned short* wtp = (unsigned short*)take(128 * 128 * 2);
    int nb = (N + 255) / 256;  // must be <= 1024
    int*   bsum   = (int*)take((size_t)nb * 4);
    (void)ws_size; (void)n_in; (void)out_size;

    hipMemsetAsync(deg, 0, (size_t)N * 4, stream);
    hipMemsetAsync(cursor, 0, (size_t)N * 4, stream);

    bn_prep<<<1, 128, 0, stream>>>(gamma, beta, rmean, rvar, bnsc, bnsh);
    w_to_bf16T<<<64, 256, 0, stream>>>(W1, wt1);
    w_to_bf16T<<<64, 256, 0, stream>>>(W2, wt2);
    w_to_bf16T<<<64, 256, 0, stream>>>(Wp1, wtp);

    count_deg<<<(E + 255) / 256, 256, 0, stream>>>(dst, deg, E);
    scan_block_reduce<<<nb, 256, 0, stream>>>(deg, bsum, N);
    scan_block_sums<<<1, 1024, 0, stream>>>(bsum, offs, nb, N);
    scan_write_offsets<<<nb, 256, 0, stream>>>(deg, bsum, offs, N);
    fill_csr<<<(E + 255) / 256, 256, 0, stream>>>(src, dst, offs, cursor, csr, E);

    int gblk = (N + 127) / 128;
    // ---- conv1 + BN + ReLU ----
    gemm_mfma<false><<<gblk, 256, 0, stream>>>(emb, wt1, a_src1, a_dst1, bufA, s_src, s_dst, N);
    edge_softmax<<<(N + 15) / 16, 256, 0, stream>>>(offs, csr, s_src, s_dst, we, invd, N);
    gat_gather<<<(N + 3) / 4, 256, 0, stream>>>(bufA, offs, csr, we, invd, b1,
                                                bnsc, bnsh, 1, bufB, N);
    // ---- conv2 ----
    gemm_mfma<true><<<gblk, 256, 0, stream>>>(bufB, wt2, a_src2, a_dst2, bufA, s_src, s_dst, N);
    edge_softmax<<<(N + 15) / 16, 256, 0, stream>>>(offs, csr, s_src, s_dst, we, invd, N);
    gat_gather<<<(N + 3) / 4, 256, 0, stream>>>(bufA, offs, csr, we, invd, b2,
                                                nullptr, nullptr, 0, bufB, N);
    // ---- link predictor (MFMA bf16, persistent) ----
    link_pred_mfma<<<1024, 256, 0, stream>>>(bufB, e0, e1, wtp, bp1, Wp2, bp2, out, Q);
}

// Round 6
// 377.302 us; speedup vs baseline: 1.1175x; 1.1175x over previous
//
#include <hip/hip_runtime.h>
#include <hip/hip_bf16.h>
#include <math.h>
#include <stdint.h>

#define NEG_SLOPE 0.2f
#define BN_EPS 1e-5f

typedef __attribute__((ext_vector_type(8))) short short8;
typedef __attribute__((ext_vector_type(4))) float float4v;

static __device__ __forceinline__ unsigned short f2bf(float f) {
    union { float f; unsigned u; } v; v.f = f;
    unsigned r = (v.u + 0x7fffu + ((v.u >> 16) & 1u)) >> 16;  // RNE
    return (unsigned short)r;
}
static __device__ __forceinline__ float bf2f(unsigned short u) {
    union { unsigned u; float f; } v; v.u = ((unsigned)u) << 16;
    return v.f;
}

// ---------------------------------------------------------------------------
// BN constant prep
// ---------------------------------------------------------------------------
__global__ __launch_bounds__(128) void bn_prep(const float* __restrict__ gamma,
                                               const float* __restrict__ beta,
                                               const float* __restrict__ rmean,
                                               const float* __restrict__ rvar,
                                               float* __restrict__ scale,
                                               float* __restrict__ shift) {
    int c = threadIdx.x;
    float s = gamma[c] * rsqrtf(rvar[c] + BN_EPS);
    scale[c] = s;
    shift[c] = beta[c] - rmean[c] * s;
}

// ---------------------------------------------------------------------------
// one-time: WT[n*128+k] = bf16(W[k*128+n])   (pre-transposed B for MFMA)
// ---------------------------------------------------------------------------
__global__ __launch_bounds__(256) void w_to_bf16T(const float* __restrict__ W,
                                                  unsigned short* __restrict__ WT) {
    int idx = blockIdx.x * 256 + threadIdx.x;  // 16384 total
    int k = idx >> 7, n = idx & 127;
    WT[n * 128 + k] = f2bf(W[idx]);
}

// ---------------------------------------------------------------------------
// CSR build
// ---------------------------------------------------------------------------
__global__ __launch_bounds__(256) void count_deg(const int* __restrict__ dst,
                                                 int* __restrict__ deg, int E) {
    int i = blockIdx.x * 256 + threadIdx.x;
    if (i < E) atomicAdd(&deg[dst[i]], 1);
}

__global__ __launch_bounds__(256) void scan_block_reduce(const int* __restrict__ deg,
                                                         int* __restrict__ bsum, int N) {
    __shared__ int s[256];
    int t = threadIdx.x;
    int i = blockIdx.x * 256 + t;
    s[t] = (i < N) ? deg[i] : 0;
    __syncthreads();
#pragma unroll
    for (int d = 128; d; d >>= 1) {
        if (t < d) s[t] += s[t + d];
        __syncthreads();
    }
    if (t == 0) bsum[blockIdx.x] = s[0];
}

__global__ __launch_bounds__(1024) void scan_block_sums(int* __restrict__ bsum,
                                                        int* __restrict__ offs,
                                                        int nb, int N) {
    __shared__ int s[1024];
    int t = threadIdx.x;
    int v = (t < nb) ? bsum[t] : 0;
    s[t] = v;
    __syncthreads();
    for (int d = 1; d < 1024; d <<= 1) {
        int u = (t >= d) ? s[t - d] : 0;
        __syncthreads();
        s[t] += u;
        __syncthreads();
    }
    if (t < nb) bsum[t] = s[t] - v;       // exclusive block base
    if (t == 1023) offs[N] = s[1023];     // total == E
}

__global__ __launch_bounds__(256) void scan_write_offsets(const int* __restrict__ deg,
                                                          const int* __restrict__ bsum,
                                                          int* __restrict__ offs, int N) {
    __shared__ int s[256];
    int t = threadIdx.x;
    int i = blockIdx.x * 256 + t;
    int v = (i < N) ? deg[i] : 0;
    s[t] = v;
    __syncthreads();
    for (int d = 1; d < 256; d <<= 1) {
        int u = (t >= d) ? s[t - d] : 0;
        __syncthreads();
        s[t] += u;
        __syncthreads();
    }
    if (i < N) offs[i] = bsum[blockIdx.x] + s[t] - v;
}

__global__ __launch_bounds__(256) void fill_csr(const int* __restrict__ src,
                                                const int* __restrict__ dst,
                                                const int* __restrict__ off,
                                                int* __restrict__ cursor,
                                                int* __restrict__ csr_src, int E) {
    int i = blockIdx.x * 256 + threadIdx.x;
    if (i < E) {
        int d = dst[i];
        int p = atomicAdd(&cursor[d], 1);
        csr_src[off[d] + p] = src[i];
    }
}

// ---------------------------------------------------------------------------
// H(bf16) = X @ W via MFMA bf16 (fp32 accum), node_scores fused in epilogue.
// Templated input: fp32 (layer 1: embedding) or bf16 (layer 2: x1).
// ---------------------------------------------------------------------------
#define LP_RS 136  // LDS row stride in bf16 elements (272 bytes)

template <bool BF16_IN>
__global__ __launch_bounds__(256) void gemm_mfma(
    const void* __restrict__ Xv,
    const unsigned short* __restrict__ WT,  // [n][k] bf16 (pre-transposed)
    const float* __restrict__ a_src, const float* __restrict__ a_dst,
    unsigned short* __restrict__ H,         // bf16 out
    float* __restrict__ s_src, float* __restrict__ s_dst, int N)
{
    __shared__ unsigned short sA[128 * LP_RS];
    __shared__ unsigned short sW[128 * LP_RS];
    const float* Xf = (const float*)Xv;
    const unsigned short* Xh = (const unsigned short*)Xv;
    int tid = threadIdx.x;
    int r0 = blockIdx.x * 128;

#pragma unroll
    for (int it = 0; it < 8; ++it) {
        int idx = it * 2048 + tid * 8;
        int n = idx >> 7, k = idx & 127;
        *(short8*)&sW[n * LP_RS + k] = *(const short8*)&WT[idx];
    }
#pragma unroll
    for (int it = 0; it < 16; ++it) {
        int r = it * 8 + (tid >> 5);
        int c = (tid & 31) * 4;
        int row = r0 + r;
        ushort4 u = make_ushort4(0, 0, 0, 0);
        if (row < N) {
            if (BF16_IN) {
                u = *(const ushort4*)&Xh[(size_t)row * 128 + c];
            } else {
                float4 x = *(const float4*)&Xf[(size_t)row * 128 + c];
                u.x = f2bf(x.x); u.y = f2bf(x.y); u.z = f2bf(x.z); u.w = f2bf(x.w);
            }
        }
        *(ushort4*)&sA[r * LP_RS + c] = u;
    }
    __syncthreads();

    int wave = tid >> 6, lane = tid & 63;
    int ln = lane & 15, quad = lane >> 4;
    int rowbase = wave * 32;

    short8 af[2][4];
#pragma unroll
    for (int m = 0; m < 2; ++m)
#pragma unroll
        for (int kt = 0; kt < 4; ++kt)
            af[m][kt] = *(const short8*)&sA[(rowbase + m * 16 + ln) * LP_RS + kt * 32 + quad * 8];

    float4v acc[2][8];
#pragma unroll
    for (int m = 0; m < 2; ++m)
#pragma unroll
        for (int n = 0; n < 8; ++n)
            acc[m][n] = float4v{0.f, 0.f, 0.f, 0.f};

#pragma unroll
    for (int n = 0; n < 8; ++n) {
#pragma unroll
        for (int kt = 0; kt < 4; ++kt) {
            short8 bf = *(const short8*)&sW[(n * 16 + ln) * LP_RS + kt * 32 + quad * 8];
            acc[0][n] = __builtin_amdgcn_mfma_f32_16x16x32_bf16(af[0][kt], bf, acc[0][n], 0, 0, 0);
            acc[1][n] = __builtin_amdgcn_mfma_f32_16x16x32_bf16(af[1][kt], bf, acc[1][n], 0, 0, 0);
        }
    }

    // epilogue: store H bf16 (C/D layout: col=ln, row=quad*4+reg) + fused scores
    float asr[8], adr[8];
#pragma unroll
    for (int n = 0; n < 8; ++n) {
        asr[n] = a_src[n * 16 + ln];
        adr[n] = a_dst[n * 16 + ln];
    }
#pragma unroll
    for (int m = 0; m < 2; ++m) {
        int rb = r0 + rowbase + m * 16 + quad * 4;
#pragma unroll
        for (int n = 0; n < 8; ++n) {
            int col = n * 16 + ln;
            float4v a = acc[m][n];
            if (rb + 0 < N) H[(size_t)(rb + 0) * 128 + col] = f2bf(a[0]);
            if (rb + 1 < N) H[(size_t)(rb + 1) * 128 + col] = f2bf(a[1]);
            if (rb + 2 < N) H[(size_t)(rb + 2) * 128 + col] = f2bf(a[2]);
            if (rb + 3 < N) H[(size_t)(rb + 3) * 128 + col] = f2bf(a[3]);
        }
#pragma unroll
        for (int r = 0; r < 4; ++r) {
            float ps = 0.f, pd = 0.f;
#pragma unroll
            for (int n = 0; n < 8; ++n) {
                float v = acc[m][n][r];
                ps = fmaf(v, asr[n], ps);
                pd = fmaf(v, adr[n], pd);
            }
#pragma unroll
            for (int o = 1; o < 16; o <<= 1) {
                ps += __shfl_xor(ps, o);
                pd += __shfl_xor(pd, o);
            }
            int row = rb + r;
            if (ln == 0 && row < N) { s_src[row] = ps; s_dst[row] = pd; }
        }
    }
}

// ---------------------------------------------------------------------------
// Per-edge softmax weights, quad (16 lanes) per node
// ---------------------------------------------------------------------------
__global__ __launch_bounds__(256) void edge_softmax(const int* __restrict__ off,
                                                    const int* __restrict__ csr,
                                                    const float* __restrict__ s_src,
                                                    const float* __restrict__ s_dst,
                                                    float* __restrict__ we,
                                                    float* __restrict__ invd, int N) {
    int tid = threadIdx.x;
    int node = blockIdx.x * 16 + (tid >> 4);
    if (node >= N) return;
    int ln = tid & 15;
    int beg = off[node], end = off[node + 1];
    float sd = s_dst[node];

    float m = -INFINITY;
    for (int i = beg + ln; i < end; i += 16) {
        float e = s_src[csr[i]] + sd;
        e = (e >= 0.f) ? e : NEG_SLOPE * e;
        we[i] = e;
        m = fmaxf(m, e);
    }
#pragma unroll
    for (int o = 8; o; o >>= 1) m = fmaxf(m, __shfl_xor(m, o));

    float sw = 0.f;
    for (int i = beg + ln; i < end; i += 16) {
        float w = expf(we[i] - m);
        we[i] = w;
        sw += w;
    }
#pragma unroll
    for (int o = 8; o; o >>= 1) sw += __shfl_xor(sw, o);
    if (ln == 0) invd[node] = 1.f / (sw + 1e-16f);
}

// ---------------------------------------------------------------------------
// Weighted gather over bf16 H: out_bf16[n,:] = (sum we*h)*invd + bias (+BN/ReLU)
// ---------------------------------------------------------------------------
__global__ __launch_bounds__(256) void gat_gather(const unsigned short* __restrict__ H,
                                                  const int* __restrict__ off,
                                                  const int* __restrict__ csr,
                                                  const float* __restrict__ we,
                                                  const float* __restrict__ invd,
                                                  const float* __restrict__ bias,
                                                  const float* __restrict__ bn_scale,
                                                  const float* __restrict__ bn_shift,
                                                  int do_bn_relu,
                                                  unsigned short* __restrict__ out, int N) {
    int node = blockIdx.x * 4 + (threadIdx.x >> 6);
    if (node >= N) return;
    int lane = threadIdx.x & 63;
    int c0 = lane * 2;
    int beg = off[node], end = off[node + 1];
    float inv = invd[node];

    float accx = 0.f, accy = 0.f;
    int i = beg;
    for (; i + 8 <= end; i += 8) {
#pragma unroll
        for (int u = 0; u < 8; ++u) {
            int s = csr[i + u];
            float w = we[i + u];
            ushort2 hv = *(const ushort2*)&H[(size_t)s * 128 + c0];
            accx = fmaf(w, bf2f(hv.x), accx);
            accy = fmaf(w, bf2f(hv.y), accy);
        }
    }
    for (; i < end; ++i) {
        int s = csr[i];
        float w = we[i];
        ushort2 hv = *(const ushort2*)&H[(size_t)s * 128 + c0];
        accx = fmaf(w, bf2f(hv.x), accx);
        accy = fmaf(w, bf2f(hv.y), accy);
    }
    float o0 = accx * inv + bias[c0];
    float o1 = accy * inv + bias[c0 + 1];
    if (do_bn_relu) {
        o0 = fmaxf(o0 * bn_scale[c0] + bn_shift[c0], 0.f);
        o1 = fmaxf(o1 * bn_scale[c0 + 1] + bn_shift[c0 + 1], 0.f);
    }
    ushort2 ov; ov.x = f2bf(o0); ov.y = f2bf(o1);
    *(ushort2*)&out[(size_t)node * 128 + c0] = ov;
}

// ---------------------------------------------------------------------------
// Link predictor v2.1: persistent waves, sW staged once/block, A-fragments
// direct from bf16 X, per-n acc consume. NO min-waves clamp (R4's 64-VGPR
// cap caused 139 MB of scratch spill traffic — Guideline 6).
// ---------------------------------------------------------------------------
__global__ __launch_bounds__(256) void link_pred_mfma(
    const unsigned short* __restrict__ X,   // bf16 x2 [N][128]
    const int* __restrict__ E0, const int* __restrict__ E1,
    const unsigned short* __restrict__ WTg, // [n][k] bf16
    const float* __restrict__ bp1,
    const float* __restrict__ Wp2,
    const float* __restrict__ bp2_p,
    float* __restrict__ out, int Q)
{
    __shared__ unsigned short sW[128 * LP_RS];
    int tid = threadIdx.x;
#pragma unroll
    for (int it = 0; it < 8; ++it) {
        int idx = it * 2048 + tid * 8;
        int n = idx >> 7, k = idx & 127;
        *(short8*)&sW[n * LP_RS + k] = *(const short8*)&WTg[idx];
    }
    __syncthreads();

    int wave = tid >> 6, lane = tid & 63;
    int ln = lane & 15, quad = lane >> 4;

    float bias[8], w2c[8];
#pragma unroll
    for (int n = 0; n < 8; ++n) {
        bias[n] = bp1[n * 16 + ln];
        w2c[n] = Wp2[n * 16 + ln];
    }
    float b2 = bp2_p[0];

    int ntiles = (Q + 31) >> 5;
    int tile0 = blockIdx.x * 4 + wave;
    int tstride = gridDim.x * 4;

    for (int t = tile0; t < ntiles; t += tstride) {
        int qbase = t * 32;
        // A fragments direct from global (layout: A[m=ln][k=quad*8+j], k-tile kt)
        short8 af[2][4];
#pragma unroll
        for (int m = 0; m < 2; ++m) {
            int q = qbase + m * 16 + ln;
            if (q >= Q) q = Q - 1;  // clamp; store is guarded
            int a = E0[q], b = E1[q];
            const unsigned short* pa = &X[(size_t)a * 128 + quad * 8];
            const unsigned short* pb = &X[(size_t)b * 128 + quad * 8];
#pragma unroll
            for (int kt = 0; kt < 4; ++kt) {
                short8 xa = *(const short8*)(pa + kt * 32);
                short8 xb = *(const short8*)(pb + kt * 32);
                short8 p;
#pragma unroll
                for (int j = 0; j < 8; ++j)
                    p[j] = (short)f2bf(bf2f((unsigned short)xa[j]) * bf2f((unsigned short)xb[j]));
                af[m][kt] = p;
            }
        }

        float r0[2] = {0.f, 0.f}, r1[2] = {0.f, 0.f}, r2[2] = {0.f, 0.f}, r3[2] = {0.f, 0.f};
#pragma unroll
        for (int n = 0; n < 8; ++n) {
            float4v a0 = float4v{bias[n], bias[n], bias[n], bias[n]};
            float4v a1 = a0;
#pragma unroll
            for (int kt = 0; kt < 4; ++kt) {
                short8 bf = *(const short8*)&sW[(n * 16 + ln) * LP_RS + kt * 32 + quad * 8];
                a0 = __builtin_amdgcn_mfma_f32_16x16x32_bf16(af[0][kt], bf, a0, 0, 0, 0);
                a1 = __builtin_amdgcn_mfma_f32_16x16x32_bf16(af[1][kt], bf, a1, 0, 0, 0);
            }
            float w = w2c[n];
            r0[0] += fmaxf(a0[0], 0.f) * w;  r0[1] += fmaxf(a1[0], 0.f) * w;
            r1[0] += fmaxf(a0[1], 0.f) * w;  r1[1] += fmaxf(a1[1], 0.f) * w;
            r2[0] += fmaxf(a0[2], 0.f) * w;  r2[1] += fmaxf(a1[2], 0.f) * w;
            r3[0] += fmaxf(a0[3], 0.f) * w;  r3[1] += fmaxf(a1[3], 0.f) * w;
        }
#pragma unroll
        for (int m = 0; m < 2; ++m) {
#pragma unroll
            for (int o = 1; o < 16; o <<= 1) {
                r0[m] += __shfl_xor(r0[m], o);
                r1[m] += __shfl_xor(r1[m], o);
                r2[m] += __shfl_xor(r2[m], o);
                r3[m] += __shfl_xor(r3[m], o);
            }
            if (ln == 0) {
                int rbase = qbase + m * 16 + quad * 4;
                float rv[4] = {r0[m], r1[m], r2[m], r3[m]};
#pragma unroll
                for (int r = 0; r < 4; ++r) {
                    int q = rbase + r;
                    if (q < Q) out[q] = 1.f / (1.f + expf(-(rv[r] + b2)));
                }
            }
        }
    }
}

// ---------------------------------------------------------------------------
extern "C" void kernel_launch(void* const* d_in, const int* in_sizes, int n_in,
                              void* d_out, int out_size, void* d_ws, size_t ws_size,
                              hipStream_t stream) {
    const float* emb    = (const float*)d_in[0];
    const float* W1     = (const float*)d_in[1];
    const float* a_src1 = (const float*)d_in[2];
    const float* a_dst1 = (const float*)d_in[3];
    const float* b1     = (const float*)d_in[4];
    const float* gamma  = (const float*)d_in[5];
    const float* beta   = (const float*)d_in[6];
    const float* rmean  = (const float*)d_in[7];
    const float* rvar   = (const float*)d_in[8];
    const float* W2     = (const float*)d_in[9];
    const float* a_src2 = (const float*)d_in[10];
    const float* a_dst2 = (const float*)d_in[11];
    const float* b2     = (const float*)d_in[12];
    const float* Wp1    = (const float*)d_in[13];
    const float* bp1    = (const float*)d_in[14];
    const float* Wp2    = (const float*)d_in[15];
    const float* bp2    = (const float*)d_in[16];
    const int* edge_index = (const int*)d_in[17];
    const int* edges      = (const int*)d_in[18];

    const int N = in_sizes[0] / 128;
    const int E = in_sizes[17] / 2;
    const int Q = in_sizes[18] / 2;
    const int* src = edge_index;
    const int* dst = edge_index + E;
    const int* e0 = edges;
    const int* e1 = edges + Q;
    float* out = (float*)d_out;

    uintptr_t base = (uintptr_t)d_ws;
    size_t cur = 0;
    auto take = [&](size_t bytes) -> void* {
        void* p = (void*)(base + cur);
        cur += (bytes + 255) & ~(size_t)255;
        return p;
    };
    unsigned short* bufA = (unsigned short*)take((size_t)N * 128 * 2);  // H (bf16)
    unsigned short* bufB = (unsigned short*)take((size_t)N * 128 * 2);  // x (bf16)
    float* s_src  = (float*)take((size_t)N * 4);
    float* s_dst  = (float*)take((size_t)N * 4);
    float* bnsc   = (float*)take(128 * 4);
    float* bnsh   = (float*)take(128 * 4);
    int*   deg    = (int*)take((size_t)N * 4);
    int*   cursor = (int*)take((size_t)N * 4);
    int*   offs   = (int*)take((size_t)(N + 1) * 4);
    int*   csr    = (int*)take((size_t)E * 4);
    float* we     = (float*)take((size_t)E * 4);
    float* invd   = (float*)take((size_t)N * 4);
    unsigned short* wt1 = (unsigned short*)take(128 * 128 * 2);
    unsigned short* wt2 = (unsigned short*)take(128 * 128 * 2);
    unsigned short* wtp = (unsigned short*)take(128 * 128 * 2);
    int nb = (N + 255) / 256;  // must be <= 1024
    int*   bsum   = (int*)take((size_t)nb * 4);
    (void)ws_size; (void)n_in; (void)out_size;

    hipMemsetAsync(deg, 0, (size_t)N * 4, stream);
    hipMemsetAsync(cursor, 0, (size_t)N * 4, stream);

    bn_prep<<<1, 128, 0, stream>>>(gamma, beta, rmean, rvar, bnsc, bnsh);
    w_to_bf16T<<<64, 256, 0, stream>>>(W1, wt1);
    w_to_bf16T<<<64, 256, 0, stream>>>(W2, wt2);
    w_to_bf16T<<<64, 256, 0, stream>>>(Wp1, wtp);

    count_deg<<<(E + 255) / 256, 256, 0, stream>>>(dst, deg, E);
    scan_block_reduce<<<nb, 256, 0, stream>>>(deg, bsum, N);
    scan_block_sums<<<1, 1024, 0, stream>>>(bsum, offs, nb, N);
    scan_write_offsets<<<nb, 256, 0, stream>>>(deg, bsum, offs, N);
    fill_csr<<<(E + 255) / 256, 256, 0, stream>>>(src, dst, offs, cursor, csr, E);

    int gblk = (N + 127) / 128;
    // ---- conv1 + BN + ReLU ----
    gemm_mfma<false><<<gblk, 256, 0, stream>>>(emb, wt1, a_src1, a_dst1, bufA, s_src, s_dst, N);
    edge_softmax<<<(N + 15) / 16, 256, 0, stream>>>(offs, csr, s_src, s_dst, we, invd, N);
    gat_gather<<<(N + 3) / 4, 256, 0, stream>>>(bufA, offs, csr, we, invd, b1,
                                                bnsc, bnsh, 1, bufB, N);
    // ---- conv2 ----
    gemm_mfma<true><<<gblk, 256, 0, stream>>>(bufB, wt2, a_src2, a_dst2, bufA, s_src, s_dst, N);
    edge_softmax<<<(N + 15) / 16, 256, 0, stream>>>(offs, csr, s_src, s_dst, we, invd, N);
    gat_gather<<<(N + 3) / 4, 256, 0, stream>>>(bufA, offs, csr, we, invd, b2,
                                                nullptr, nullptr, 0, bufB, N);
    // ---- link predictor (MFMA bf16, persistent, 2 tiles/wave) ----
    int ntiles = (Q + 31) / 32;
    int lblk = (ntiles + 7) / 8;  // each block = 4 waves, 2 tiles/wave
    link_pred_mfma<<<lblk, 256, 0, stream>>>(bufB, e0, e1, wtp, bp1, Wp2, bp2, out, Q);
}